// Round 2
// baseline (2392.017 us; speedup 1.0000x reference)
//
#include <hip/hip_runtime.h>

#define NROWS 32768
#define KC 8192
#define D4 64

// ---------------- kernel 1: bit-exact numpy pairwise row norm ----------------
// Replicates np.sum(z*z, axis=-1) for n=256 contiguous f32:
//   pairwise_sum(a,256) = pw128(a) + pw128(a+128)
//   pw128: r[j]=a[j]; for i=8..120 step 8: r[j]+=a[i+j];
//          res = ((r0+r1)+(r2+r3))+((r4+r5)+(r6+r7))
// contract(off): squares must be rounded to f32 BEFORE the adds (numpy
// materializes z*z first) — no fma fusion allowed here.
__global__ __launch_bounds__(256) void vq_znorm(const float* __restrict__ z,
                                                float* __restrict__ An) {
#pragma clang fp contract(off)
  const int row = blockIdx.x * 256 + threadIdx.x;
  const float* a = z + (size_t)row * 256;
  float halves[2];
#pragma unroll
  for (int h = 0; h < 2; ++h) {
    const float* p = a + h * 128;
    float r[8];
#pragma unroll
    for (int j = 0; j < 8; ++j) {
      const float v = p[j];
      r[j] = v * v;
    }
    for (int i = 8; i < 128; i += 8) {
#pragma unroll
      for (int j = 0; j < 8; ++j) {
        const float v = p[i + j];
        r[j] += v * v;
      }
    }
    halves[h] = ((r[0] + r[1]) + (r[2] + r[3])) + ((r[4] + r[5]) + (r[6] + r[7]));
  }
  An[row] = halves[0] + halves[1];
}

// ---------------- kernel 2: fused f32 score + argmin (np semantics) ----------------
// score_k = fl(A_n - 2*p_nk), p accumulated as a strict k-ordered f32 FMA
// chain (emulating BLAS sgemm micro-kernel). argmin with lowest-index ties.
// block: 256 thr (tx=tid&15 codes-dim, ty=tid>>4 rows-dim)
// tile: 64 rows x 64 codes, D chunked by 128. LDS 64KB, 2 blocks/CU.
__global__ __launch_bounds__(256) void vq_phase1(
    const float* __restrict__ z, const float* __restrict__ emb,
    const float* __restrict__ An, int* __restrict__ idxo) {
  __shared__ float4 zs[64 * 32];  // [row][col4 ^ (row&15)]
  __shared__ float4 es[64 * 32];
  const int tid = threadIdx.x;
  const int tx = tid & 15;
  const int ty = tid >> 4;
  const int row0 = blockIdx.x * 64;
  const float4* z4 = (const float4*)z;
  const float4* e4 = (const float4*)emb;

  float Arow[4];
#pragma unroll
  for (int i = 0; i < 4; ++i) Arow[i] = An[row0 + ty + 16 * i];

  float m1[4];
  int i1[4];
#pragma unroll
  for (int i = 0; i < 4; ++i) { m1[i] = 3.4e38f; i1[i] = 0; }

  for (int t = 0; t < KC / 64; ++t) {
    const int c0 = t * 64;
    float acc[4][4];
#pragma unroll
    for (int i = 0; i < 4; ++i)
#pragma unroll
      for (int j = 0; j < 4; ++j) acc[i][j] = 0.f;

#pragma unroll
    for (int ch = 0; ch < 2; ++ch) {
      __syncthreads();  // protect previous phase's readers before overwrite
#pragma unroll
      for (int s = 0; s < 8; ++s) {
        const int id = tid + 256 * s;
        const int r = id >> 5, c = id & 31;
        const int sc = c ^ (r & 15);
        zs[r * 32 + sc] = z4[(size_t)(row0 + r) * D4 + ch * 32 + c];
        es[r * 32 + sc] = e4[(size_t)(c0 + r) * D4 + ch * 32 + c];
      }
      __syncthreads();
      // strict d-ascending FMA chain per (row,code): ch*128 + d4*4 + {x,y,z,w}
#pragma unroll 8
      for (int d4 = 0; d4 < 32; ++d4) {
        float4 zv[4], ev[4];
        const int zc = d4 ^ ty;   // physical col for z rows (row&15 == ty)
        const int ec = d4 ^ tx;   // physical col for e rows (row&15 == tx)
#pragma unroll
        for (int i = 0; i < 4; ++i) zv[i] = zs[(ty + 16 * i) * 32 + zc];
#pragma unroll
        for (int j = 0; j < 4; ++j) ev[j] = es[(tx + 16 * j) * 32 + ec];
#pragma unroll
        for (int i = 0; i < 4; ++i)
#pragma unroll
          for (int j = 0; j < 4; ++j) {
            acc[i][j] = fmaf(zv[i].x, ev[j].x, acc[i][j]);
            acc[i][j] = fmaf(zv[i].y, ev[j].y, acc[i][j]);
            acc[i][j] = fmaf(zv[i].z, ev[j].z, acc[i][j]);
            acc[i][j] = fmaf(zv[i].w, ev[j].w, acc[i][j]);
          }
      }
    }
    // scores for this tile; ascending code order per thread keeps first-min
#pragma unroll
    for (int j = 0; j < 4; ++j) {
      const int c = c0 + tx + 16 * j;
#pragma unroll
      for (int i = 0; i < 4; ++i) {
        const float scv = Arow[i] - 2.0f * acc[i][j];  // fl(A - 2p), fusion-safe
        if (scv < m1[i]) { m1[i] = scv; i1[i] = c; }
      }
    }
  }
  // reduce across the 16 tx lanes; ties -> lowest index
#pragma unroll
  for (int i = 0; i < 4; ++i) {
    float a1 = m1[i];
    int ai = i1[i];
#pragma unroll
    for (int off = 1; off < 16; off <<= 1) {
      const float b1 = __shfl_xor(a1, off, 64);
      const int bi = __shfl_xor(ai, off, 64);
      if (b1 < a1 || (b1 == a1 && bi < ai)) { a1 = b1; ai = bi; }
    }
    if (tx == 0) idxo[row0 + ty + 16 * i] = ai;
  }
}

// ---------------- kernel 3: gather output rows ----------------
__global__ __launch_bounds__(256) void vq_gather(const float* __restrict__ emb,
                                                 const int* __restrict__ idxo,
                                                 float* __restrict__ out) {
  const float4* e4 = (const float4*)emb;
  float4* o4 = (float4*)out;
  const int id = blockIdx.x * 256 + threadIdx.x;  // grid 2048
#pragma unroll
  for (int t = 0; t < 4; ++t) {
    const int g = id + t * 524288;  // 4*524288 = 32768*64 float4
    const int nrow = g >> 6;
    const int d4c = g & 63;
    o4[g] = e4[(size_t)idxo[nrow] * D4 + d4c];
  }
}

extern "C" void kernel_launch(void* const* d_in, const int* in_sizes, int n_in,
                              void* d_out, int out_size, void* d_ws, size_t ws_size,
                              hipStream_t stream) {
  const float* z = (const float*)d_in[0];    // [32768, 256] f32
  const float* emb = (const float*)d_in[1];  // [8192, 256] f32
  float* out = (float*)d_out;                // [32768, 256] f32

  float* ws = (float*)d_ws;
  float* An = ws;                  // 32768 f32
  int* idx = (int*)(An + NROWS);   // 32768 i32

  vq_znorm<<<NROWS / 256, 256, 0, stream>>>(z, An);
  vq_phase1<<<NROWS / 64, 256, 0, stream>>>(z, emb, An, idx);
  vq_gather<<<2048, 256, 0, stream>>>(emb, idx, out);
}

// Round 3
// 623.808 us; speedup vs baseline: 3.8345x; 3.8345x over previous
//
#include <hip/hip_runtime.h>

#define NROWS 32768
#define KC 8192
#define DDIM 256
#define D4 64
#define CAP 128
#define DELTA 4e-4f

typedef _Float16 half8 __attribute__((ext_vector_type(8)));
typedef float f32x4 __attribute__((ext_vector_type(4)));
typedef unsigned int uint;
typedef const __attribute__((address_space(1))) unsigned int* gptr_u32;
typedef __attribute__((address_space(3))) unsigned int* lptr_u32;

union H4 { ushort4 u; _Float16 h[4]; };

// ---------------- kernel 1: bit-exact numpy pairwise row norm (verified) ----------------
__global__ __launch_bounds__(256) void vq_znorm(const float* __restrict__ z,
                                                float* __restrict__ An) {
#pragma clang fp contract(off)
  const int row = blockIdx.x * 256 + threadIdx.x;
  const float* a = z + (size_t)row * 256;
  float halves[2];
#pragma unroll
  for (int h = 0; h < 2; ++h) {
    const float* p = a + h * 128;
    float r[8];
#pragma unroll
    for (int j = 0; j < 8; ++j) { const float v = p[j]; r[j] = v * v; }
    for (int i = 8; i < 128; i += 8) {
#pragma unroll
      for (int j = 0; j < 8; ++j) { const float v = p[i + j]; r[j] += v * v; }
    }
    halves[h] = ((r[0] + r[1]) + (r[2] + r[3])) + ((r[4] + r[5]) + (r[6] + r[7]));
  }
  An[row] = halves[0] + halves[1];
}

// ---------------- kernel 2: f32 -> f16 conversion (+ scale e by 2^13) + init ----------------
__global__ __launch_bounds__(256) void vq_convert(const float* __restrict__ z,
                                                  const float* __restrict__ emb,
                                                  _Float16* __restrict__ z16,
                                                  _Float16* __restrict__ e16,
                                                  uint* __restrict__ rowmin,
                                                  int* __restrict__ cnt) {
  const int tid = blockIdx.x * 256 + threadIdx.x;  // grid 2048 -> 524288 threads
  const float4* z4 = (const float4*)z;
  const float4* e4 = (const float4*)emb;
  ushort4* z16u = (ushort4*)z16;
  ushort4* e16u = (ushort4*)e16;
#pragma unroll
  for (int t = 0; t < 4; ++t) {
    const int i = tid + t * 524288;  // 4*524288 = 2097152 = 32768*64
    const float4 v = z4[i];
    H4 o;
    o.h[0] = (_Float16)v.x; o.h[1] = (_Float16)v.y;
    o.h[2] = (_Float16)v.z; o.h[3] = (_Float16)v.w;
    z16u[i] = o.u;
  }
  {
    const int i = tid;  // 524288 = 8192*64
    const float4 v = e4[i];
    H4 o;
    o.h[0] = (_Float16)(v.x * 8192.0f); o.h[1] = (_Float16)(v.y * 8192.0f);
    o.h[2] = (_Float16)(v.z * 8192.0f); o.h[3] = (_Float16)(v.w * 8192.0f);
    e16u[i] = o.u;
  }
  if (tid < NROWS) { rowmin[tid] = 0x7F800000u; cnt[tid] = 0; }  // +inf, 0
}

// ---------------- kernel 3: f16 MFMA GEMM + fused min/candidate filter ----------------
// 128x128 tile, BK=32, 4 waves (2x2, each 64x64 via 16x16x32 MFMA), m97 structure.
__global__ __launch_bounds__(256) void vq_gemm_filter(
    const _Float16* __restrict__ z16, const _Float16* __restrict__ e16,
    const float* __restrict__ An, uint* __restrict__ rowmin,
    int* __restrict__ cnt, int* __restrict__ list) {
  __shared__ _Float16 As[128 * 32];
  __shared__ _Float16 Bs[128 * 32];
  const int bid = blockIdx.x;                 // 16384 blocks
  const int swz = (bid & 7) * 2048 + (bid >> 3);  // XCD swizzle (16384%8==0, bijective)
  const int nIdx = swz >> 8;                  // 0..63  codes panel (major -> L2-hot B)
  const int mIdx = swz & 255;                 // 0..255 rows panel
  const int brow = mIdx * 128, bcol = nIdx * 128;
  const int tid = threadIdx.x;
  const int lane = tid & 63, w = tid >> 6;
  const int wr = w >> 1, wc = w & 1;
  const int l15 = lane & 15, l4 = lane >> 4;

  f32x4 acc[4][4] = {{{0.f}}};

  for (int ks = 0; ks < 8; ++ks) {
    const int k0 = ks * 32;
    __syncthreads();
#pragma unroll
    for (int i = 0; i < 2; ++i) {
      const int c = tid + 256 * i;            // 0..511 chunks of 8 f16
      const int r = c >> 2, off = (c & 3) * 8;
      __builtin_amdgcn_global_load_lds(
          (gptr_u32)(z16 + (size_t)(brow + r) * DDIM + k0 + off),
          (lptr_u32)(As + c * 8), 16, 0, 0);
      __builtin_amdgcn_global_load_lds(
          (gptr_u32)(e16 + (size_t)(bcol + r) * DDIM + k0 + off),
          (lptr_u32)(Bs + c * 8), 16, 0, 0);
    }
    __syncthreads();  // compiler drains vmcnt(0) before s_barrier
    half8 af[4], bf[4];
#pragma unroll
    for (int m = 0; m < 4; ++m)
      af[m] = *(const half8*)(As + (wr * 64 + m * 16 + l15) * 32 + l4 * 8);
#pragma unroll
    for (int n = 0; n < 4; ++n)
      bf[n] = *(const half8*)(Bs + (wc * 64 + n * 16 + l15) * 32 + l4 * 8);
#pragma unroll
    for (int m = 0; m < 4; ++m)
#pragma unroll
      for (int n = 0; n < 4; ++n)
        acc[m][n] = __builtin_amdgcn_mfma_f32_16x16x32_f16(af[m], bf[n], acc[m][n], 0, 0, 0);
  }

  // ---- epilogue: approx scores, running-min, candidate append ----
  // C layout: col = lane&15, row = (lane>>4)*4 + reg  (verified m89/m91)
  float An_r[4][4];
#pragma unroll
  for (int m = 0; m < 4; ++m)
#pragma unroll
    for (int r = 0; r < 4; ++r)
      An_r[m][r] = An[brow + wr * 64 + m * 16 + l4 * 4 + r];

  float rmin[4][4];
#pragma unroll
  for (int m = 0; m < 4; ++m)
#pragma unroll
    for (int r = 0; r < 4; ++r) rmin[m][r] = 3.4e38f;
#pragma unroll
  for (int m = 0; m < 4; ++m)
#pragma unroll
    for (int n = 0; n < 4; ++n)
#pragma unroll
      for (int r = 0; r < 4; ++r) {
        const float s = fmaf(acc[m][n][r], -0x1p-12f, An_r[m][r]);  // A - 2*p'*2^-13
        acc[m][n][r] = s;
        rmin[m][r] = fminf(rmin[m][r], s);
      }
  // row-min across the 16 col-lanes
#pragma unroll
  for (int off = 1; off < 16; off <<= 1)
#pragma unroll
    for (int m = 0; m < 4; ++m)
#pragma unroll
      for (int r = 0; r < 4; ++r)
        rmin[m][r] = fminf(rmin[m][r], __shfl_xor(rmin[m][r], off, 64));

  float cur[4][4];
#pragma unroll
  for (int m = 0; m < 4; ++m)
#pragma unroll
    for (int r = 0; r < 4; ++r) {
      const int row = brow + wr * 64 + m * 16 + l4 * 4 + r;
      float oldf = 3.4e38f;
      if (l15 == 0)  // scores > 0 always -> uint order == float order
        oldf = __uint_as_float(atomicMin(rowmin + row, __float_as_uint(rmin[m][r])));
      oldf = __shfl(oldf, lane & 48, 64);
      cur[m][r] = fminf(oldf, rmin[m][r]) + DELTA;
    }
#pragma unroll
  for (int m = 0; m < 4; ++m)
#pragma unroll
    for (int n = 0; n < 4; ++n)
#pragma unroll
      for (int r = 0; r < 4; ++r) {
        if (acc[m][n][r] <= cur[m][r]) {
          const int row = brow + wr * 64 + m * 16 + l4 * 4 + r;
          const int code = bcol + wc * 64 + n * 16 + l15;
          const int pos = atomicAdd(cnt + row, 1);
          if (pos < CAP) list[row * CAP + pos] = code;
        }
      }
}

// ---------------- kernel 4: exact recheck (bit-exact np chain) ----------------
__global__ __launch_bounds__(64) void vq_recheck(
    const float* __restrict__ z, const float* __restrict__ emb,
    const float* __restrict__ An, const int* __restrict__ cnt,
    const int* __restrict__ list, int* __restrict__ idxo) {
  const int row = blockIdx.x;
  const int lane = threadIdx.x;
  const int nc = cnt[row];
  const float Ar = An[row];
  const float4* z4r = (const float4*)z + (size_t)row * D4;
  const float4* e4 = (const float4*)emb;
  float bs = 3.4e38f;
  int bi = 0x7fffffff;
  if (nc <= CAP) {
    for (int c = lane; c < nc; c += 64) {
      const int code = list[row * CAP + c];
      float p = 0.f;
      for (int d = 0; d < D4; ++d) {
        const float4 zv = z4r[d];
        const float4 ev = e4[(size_t)code * D4 + d];
        p = fmaf(zv.x, ev.x, p); p = fmaf(zv.y, ev.y, p);
        p = fmaf(zv.z, ev.z, p); p = fmaf(zv.w, ev.w, p);
      }
      const float s = Ar - 2.0f * p;  // fl(A-2p), 2p exact
      if (s < bs || (s == bs && code < bi)) { bs = s; bi = code; }
    }
  } else {  // overflow fallback: exact full scan (correct regardless of filter)
    for (int code = lane; code < KC; code += 64) {
      float p = 0.f;
      for (int d = 0; d < D4; ++d) {
        const float4 zv = z4r[d];
        const float4 ev = e4[(size_t)code * D4 + d];
        p = fmaf(zv.x, ev.x, p); p = fmaf(zv.y, ev.y, p);
        p = fmaf(zv.z, ev.z, p); p = fmaf(zv.w, ev.w, p);
      }
      const float s = Ar - 2.0f * p;
      if (s < bs || (s == bs && code < bi)) { bs = s; bi = code; }
    }
  }
#pragma unroll
  for (int off = 1; off < 64; off <<= 1) {
    const float os = __shfl_xor(bs, off, 64);
    const int oi = __shfl_xor(bi, off, 64);
    if (os < bs || (os == bs && oi < bi)) { bs = os; bi = oi; }
  }
  if (lane == 0) idxo[row] = bi;
}

// ---------------- kernel 5: gather output rows ----------------
__global__ __launch_bounds__(256) void vq_gather(const float* __restrict__ emb,
                                                 const int* __restrict__ idxo,
                                                 float* __restrict__ out) {
  const float4* e4 = (const float4*)emb;
  float4* o4 = (float4*)out;
  const int id = blockIdx.x * 256 + threadIdx.x;  // grid 2048
#pragma unroll
  for (int t = 0; t < 4; ++t) {
    const int g = id + t * 524288;
    const int nrow = g >> 6;
    const int d4c = g & 63;
    o4[g] = e4[(size_t)idxo[nrow] * D4 + d4c];
  }
}

extern "C" void kernel_launch(void* const* d_in, const int* in_sizes, int n_in,
                              void* d_out, int out_size, void* d_ws, size_t ws_size,
                              hipStream_t stream) {
  const float* z = (const float*)d_in[0];    // [32768, 256] f32
  const float* emb = (const float*)d_in[1];  // [8192, 256] f32
  float* out = (float*)d_out;                // [32768, 256] f32

  // ws layout (bytes):
  char* wsb = (char*)d_ws;
  float* An = (float*)(wsb);                        // 128 KB
  uint* rowmin = (uint*)(wsb + (128 << 10));        // 128 KB
  int* cnt = (int*)(wsb + (256 << 10));             // 128 KB
  int* idx = (int*)(wsb + (384 << 10));             // 128 KB
  int* list = (int*)(wsb + (512 << 10));            // 16 MB
  _Float16* z16 = (_Float16*)(wsb + (512 << 10) + (16 << 20));  // 16 MB
  _Float16* e16 = (_Float16*)(wsb + (512 << 10) + (32 << 20));  // 4 MB

  vq_znorm<<<NROWS / 256, 256, 0, stream>>>(z, An);
  vq_convert<<<2048, 256, 0, stream>>>(z, emb, z16, e16, rowmin, cnt);
  vq_gemm_filter<<<16384, 256, 0, stream>>>(z16, e16, An, rowmin, cnt, list);
  vq_recheck<<<NROWS, 64, 0, stream>>>(z, emb, An, cnt, list, idx);
  vq_gather<<<2048, 256, 0, stream>>>(emb, idx, out);
}

// Round 5
// 557.507 us; speedup vs baseline: 4.2906x; 1.1189x over previous
//
#include <hip/hip_runtime.h>

#define NROWS 32768
#define KC 8192
#define DDIM 256
#define D4 64
#define CAP 128
#define DELTA 4e-4f
#define MT 128
#define NSEG 8
#define SEGC (KC / NSEG)   // 1024 codes per block
#define PAN 64             // codes per panel
#define NPAN (SEGC / PAN)  // 16 panels

typedef _Float16 half8 __attribute__((ext_vector_type(8)));
typedef float f32x4 __attribute__((ext_vector_type(4)));
typedef unsigned int uint;
typedef const __attribute__((address_space(1))) unsigned int* gptr_u32;
typedef __attribute__((address_space(3))) unsigned int* lptr_u32;

union H4 { ushort4 u; _Float16 h[4]; };

// ---------------- kernel 1: bit-exact numpy pairwise row norm (float4 loads) ----------------
__global__ __launch_bounds__(256) void vq_znorm(const float* __restrict__ z,
                                                float* __restrict__ An) {
#pragma clang fp contract(off)
  const int row = blockIdx.x * 256 + threadIdx.x;
  const float4* p4 = (const float4*)(z + (size_t)row * 256);
  float halves[2];
#pragma unroll
  for (int h = 0; h < 2; ++h) {
    float r[8];
    float4 a = p4[h * 32 + 0], b = p4[h * 32 + 1];
    r[0] = a.x * a.x; r[1] = a.y * a.y; r[2] = a.z * a.z; r[3] = a.w * a.w;
    r[4] = b.x * b.x; r[5] = b.y * b.y; r[6] = b.z * b.z; r[7] = b.w * b.w;
    for (int i = 1; i < 16; ++i) {  // 8-element chunks in numpy order
      a = p4[h * 32 + i * 2];
      b = p4[h * 32 + i * 2 + 1];
      r[0] += a.x * a.x; r[1] += a.y * a.y; r[2] += a.z * a.z; r[3] += a.w * a.w;
      r[4] += b.x * b.x; r[5] += b.y * b.y; r[6] += b.z * b.z; r[7] += b.w * b.w;
    }
    halves[h] = ((r[0] + r[1]) + (r[2] + r[3])) + ((r[4] + r[5]) + (r[6] + r[7]));
  }
  An[row] = halves[0] + halves[1];
}

// ---------------- kernel 2: f32 -> f16 conversion (+ scale e by 2^13) + init ----------------
__global__ __launch_bounds__(256) void vq_convert(const float* __restrict__ z,
                                                  const float* __restrict__ emb,
                                                  _Float16* __restrict__ z16,
                                                  _Float16* __restrict__ e16,
                                                  uint* __restrict__ rowmin,
                                                  int* __restrict__ cnt) {
  const int tid = blockIdx.x * 256 + threadIdx.x;  // 524288 threads
  const float4* z4 = (const float4*)z;
  const float4* e4 = (const float4*)emb;
  ushort4* z16u = (ushort4*)z16;
  ushort4* e16u = (ushort4*)e16;
#pragma unroll
  for (int t = 0; t < 4; ++t) {
    const int i = tid + t * 524288;
    const float4 v = z4[i];
    H4 o;
    o.h[0] = (_Float16)v.x; o.h[1] = (_Float16)v.y;
    o.h[2] = (_Float16)v.z; o.h[3] = (_Float16)v.w;
    z16u[i] = o.u;
  }
  {
    const int i = tid;  // 524288 = 8192*64
    const float4 v = e4[i];
    H4 o;
    o.h[0] = (_Float16)(v.x * 8192.0f); o.h[1] = (_Float16)(v.y * 8192.0f);
    o.h[2] = (_Float16)(v.z * 8192.0f); o.h[3] = (_Float16)(v.w * 8192.0f);
    e16u[i] = o.u;
  }
  if (tid < NROWS) { rowmin[tid] = 0x7F800000u; cnt[tid] = 0; }
}

// ---------------- kernel 3: z-stationary f16 MFMA GEMM + fused filter ----------------
// grid 2048 = 256 M-tiles(128 rows) x 8 N-segments(1024 codes); seg = bid&7 (XCD-affine).
// 4 waves; wave w: rows [w*32, w*32+32), af[2][8] register-resident (full K).
// 16 panels of 64 codes, double-buffered LDS, one barrier per panel.
__global__ __launch_bounds__(256) void vq_gemm_filter(
    const _Float16* __restrict__ z16, const _Float16* __restrict__ e16,
    const float* __restrict__ An, uint* __restrict__ rowmin,
    int* __restrict__ cnt, int* __restrict__ list) {
  __shared__ _Float16 smem[32768];  // 64KB: z-stage, then e-panel dbuf (2x32KB)
  const int bid = blockIdx.x;
  const int seg = bid & 7, mIdx = bid >> 3;
  const int brow = mIdx * MT;
  const int c0seg = seg * SEGC;
  const int tid = threadIdx.x;
  const int lane = tid & 63, w = tid >> 6;
  const int l15 = lane & 15, l4 = lane >> 4;
  const int wrow = w * 32;

  // ---- stage z tile (128x256 f16 = 64KB), source pre-swizzled: slotL = slotP ^ (row&31)
#pragma unroll
  for (int i = 0; i < 16; ++i) {
    const int c = tid + 256 * i;  // [0,4096) 16B chunks
    const int r = c >> 5, sl = (c & 31) ^ (r & 31);
    __builtin_amdgcn_global_load_lds(
        (gptr_u32)(z16 + (size_t)(brow + r) * DDIM + sl * 8),
        (lptr_u32)(smem + c * 8), 16, 0, 0);
  }
  __syncthreads();
  // ---- af register-resident: af[m][k] rows wrow+m*16+l15, k-chunk k*32 + l4*8
  half8 af[2][8];
#pragma unroll
  for (int m = 0; m < 2; ++m) {
    const int row = wrow + m * 16 + l15;
#pragma unroll
    for (int k = 0; k < 8; ++k) {
      const int sl = (k * 4 + l4) ^ (row & 31);
      af[m][k] = *(const half8*)(smem + row * 256 + sl * 8);
    }
  }
  __syncthreads();  // everyone done reading z region before overwrite

  float An_r[2][4];
#pragma unroll
  for (int m = 0; m < 2; ++m) {
    const f32x4 a4 = *(const f32x4*)(An + brow + wrow + m * 16 + l4 * 4);
#pragma unroll
    for (int r = 0; r < 4; ++r) An_r[m][r] = a4[r];
  }

  float rl[2][4], g[2][4], thr[2][4];
#pragma unroll
  for (int m = 0; m < 2; ++m)
#pragma unroll
    for (int r = 0; r < 4; ++r) { rl[m][r] = 3.4e38f; g[m][r] = 3.4e38f; thr[m][r] = 3.4e38f; }

  // prologue: stage panel 0 into buffer 0
  {
    const int cb = c0seg;
#pragma unroll
    for (int i = 0; i < 8; ++i) {
      const int c = tid + 256 * i;  // [0,2048)
      const int r = c >> 5, sl = (c & 31) ^ (r & 31);
      __builtin_amdgcn_global_load_lds(
          (gptr_u32)(e16 + (size_t)(cb + r) * DDIM + sl * 8),
          (lptr_u32)(smem + c * 8), 16, 0, 0);
    }
  }
  __syncthreads();

  for (int p = 0; p < NPAN; ++p) {
    const int curoff = (p & 1) << 14;   // 16384 f16 elements per buffer
    const int nxtoff = curoff ^ 16384;
    if (p + 1 < NPAN) {  // stage next panel into the other buffer
      const int cb = c0seg + (p + 1) * PAN;
#pragma unroll
      for (int i = 0; i < 8; ++i) {
        const int c = tid + 256 * i;
        const int r = c >> 5, sl = (c & 31) ^ (r & 31);
        __builtin_amdgcn_global_load_lds(
            (gptr_u32)(e16 + (size_t)(cb + r) * DDIM + sl * 8),
            (lptr_u32)(smem + nxtoff + c * 8), 16, 0, 0);
      }
    }
    f32x4 acc[2][4] = {{{0.f}}};
#pragma unroll
    for (int k = 0; k < 8; ++k) {
      half8 bf[4];
#pragma unroll
      for (int n = 0; n < 4; ++n) {
        const int crow = n * 16 + l15;
        const int sl = (k * 4 + l4) ^ (crow & 31);
        bf[n] = *(const half8*)(smem + curoff + crow * 256 + sl * 8);
      }
#pragma unroll
      for (int m = 0; m < 2; ++m)
#pragma unroll
        for (int n = 0; n < 4; ++n)
          acc[m][n] = __builtin_amdgcn_mfma_f32_16x16x32_f16(af[m][k], bf[n], acc[m][n], 0, 0, 0);
    }

    // ---- epilogue: scores, panel row-min, threshold, candidate append ----
    float pm[2][4];
#pragma unroll
    for (int m = 0; m < 2; ++m)
#pragma unroll
      for (int r = 0; r < 4; ++r) pm[m][r] = 3.4e38f;
#pragma unroll
    for (int m = 0; m < 2; ++m)
#pragma unroll
      for (int n = 0; n < 4; ++n)
#pragma unroll
        for (int r = 0; r < 4; ++r) {
          const float s = fmaf(acc[m][n][r], -0x1p-12f, An_r[m][r]);  // A - 2p
          acc[m][n][r] = s;
          pm[m][r] = fminf(pm[m][r], s);
        }
#pragma unroll
    for (int off = 1; off < 16; off <<= 1)
#pragma unroll
      for (int m = 0; m < 2; ++m)
#pragma unroll
        for (int r = 0; r < 4; ++r)
          pm[m][r] = fminf(pm[m][r], __shfl_xor(pm[m][r], off, 64));

    bool anyf = false;
#pragma unroll
    for (int m = 0; m < 2; ++m)
#pragma unroll
      for (int r = 0; r < 4; ++r) {
        if (pm[m][r] < rl[m][r]) {
          rl[m][r] = pm[m][r];
          if (l15 == 0) {  // scores always > 0 -> uint order == float order
            const int row = brow + wrow + m * 16 + l4 * 4 + r;
            const uint old = atomicMin(rowmin + row, __float_as_uint(pm[m][r]));
            g[m][r] = fminf(g[m][r], __uint_as_float(old));
          }
        }
        const float t = fminf(g[m][r], rl[m][r]) + DELTA;  // valid on l15==0
        thr[m][r] = __shfl(t, lane & 48, 64);
        anyf |= (pm[m][r] <= thr[m][r]);
      }
    if (__any(anyf)) {
#pragma unroll
      for (int m = 0; m < 2; ++m)
#pragma unroll
        for (int n = 0; n < 4; ++n)
#pragma unroll
          for (int r = 0; r < 4; ++r) {
            if (acc[m][n][r] <= thr[m][r]) {
              const int row = brow + wrow + m * 16 + l4 * 4 + r;
              const int code = c0seg + p * PAN + n * 16 + l15;
              const int pos = atomicAdd(cnt + row, 1);
              if (pos < CAP) list[(size_t)row * CAP + pos] = code;
            }
          }
    }
    __syncthreads();  // next-panel staging visible; cur buffer free for reuse
  }
}

// ---------------- kernel 4: exact recheck (bit-exact np chain) + gather ----------------
__global__ __launch_bounds__(256) void vq_recheck_gather(
    const float* __restrict__ z, const float* __restrict__ emb,
    const float* __restrict__ An, const int* __restrict__ cnt,
    const int* __restrict__ list, float* __restrict__ out) {
  const int row = blockIdx.x * 4 + (threadIdx.x >> 6);
  const int lane = threadIdx.x & 63;
  const int nc = cnt[row];
  const float Ar = An[row];
  const float4* z4r = (const float4*)z + (size_t)row * D4;
  const float4* e4 = (const float4*)emb;
  float bs = 3.4e38f;
  int bi = 0x7fffffff;
  if (nc <= CAP) {
    for (int c = lane; c < nc; c += 64) {
      const int code = list[(size_t)row * CAP + c];
      float p = 0.f;
      for (int d = 0; d < D4; ++d) {
        const float4 zv = z4r[d];
        const float4 ev = e4[(size_t)code * D4 + d];
        p = fmaf(zv.x, ev.x, p); p = fmaf(zv.y, ev.y, p);
        p = fmaf(zv.z, ev.z, p); p = fmaf(zv.w, ev.w, p);
      }
      const float s = Ar - 2.0f * p;
      if (s < bs || (s == bs && code < bi)) { bs = s; bi = code; }
    }
  } else {  // overflow fallback: exact full scan
    for (int code = lane; code < KC; code += 64) {
      float p = 0.f;
      for (int d = 0; d < D4; ++d) {
        const float4 zv = z4r[d];
        const float4 ev = e4[(size_t)code * D4 + d];
        p = fmaf(zv.x, ev.x, p); p = fmaf(zv.y, ev.y, p);
        p = fmaf(zv.z, ev.z, p); p = fmaf(zv.w, ev.w, p);
      }
      const float s = Ar - 2.0f * p;
      if (s < bs || (s == bs && code < bi)) { bs = s; bi = code; }
    }
  }
#pragma unroll
  for (int off = 1; off < 64; off <<= 1) {
    const float os = __shfl_xor(bs, off, 64);
    const int oi = __shfl_xor(bi, off, 64);
    if (os < bs || (os == bs && oi < bi)) { bs = os; bi = oi; }
  }
  // all 64 lanes now hold the winner; gather the output row
  const float4 v = e4[(size_t)bi * D4 + lane];
  ((float4*)out)[(size_t)row * D4 + lane] = v;
}

extern "C" void kernel_launch(void* const* d_in, const int* in_sizes, int n_in,
                              void* d_out, int out_size, void* d_ws, size_t ws_size,
                              hipStream_t stream) {
  const float* z = (const float*)d_in[0];    // [32768, 256] f32
  const float* emb = (const float*)d_in[1];  // [8192, 256] f32
  float* out = (float*)d_out;                // [32768, 256] f32

  char* wsb = (char*)d_ws;
  float* An = (float*)(wsb);                        // 128 KB
  uint* rowmin = (uint*)(wsb + (128 << 10));        // 128 KB
  int* cnt = (int*)(wsb + (256 << 10));             // 128 KB
  int* list = (int*)(wsb + (512 << 10));            // 16 MB
  _Float16* z16 = (_Float16*)(wsb + (512 << 10) + (16 << 20));  // 16 MB
  _Float16* e16 = (_Float16*)(wsb + (512 << 10) + (32 << 20));  // 4 MB

  vq_znorm<<<NROWS / 256, 256, 0, stream>>>(z, An);
  vq_convert<<<2048, 256, 0, stream>>>(z, emb, z16, e16, rowmin, cnt);
  vq_gemm_filter<<<2048, 256, 0, stream>>>(z16, e16, An, rowmin, cnt, list);
  vq_recheck_gather<<<NROWS / 4, 256, 0, stream>>>(z, emb, An, cnt, list, out);
}